// Round 1
// baseline (74394.495 us; speedup 1.0000x reference)
//
#include <hip/hip_runtime.h>
#include <math.h>

#define BATCH 8
#define CH 64
#define HH 256
#define WW 256
#define HID 512
#define NE 4

// ---------------- K1: per-(b,c) spatial mean -> g[8*64] ----------------
__global__ __launch_bounds__(256) void mean_kernel(const float* __restrict__ x,
                                                   float* __restrict__ g) {
    int bc = blockIdx.x;  // 0..511
    const float* p = x + (size_t)bc * (HH * WW);
    float s = 0.f;
    for (int i = threadIdx.x; i < HH * WW; i += 256) s += p[i];
    __shared__ float red[256];
    red[threadIdx.x] = s;
    __syncthreads();
    for (int off = 128; off > 0; off >>= 1) {
        if (threadIdx.x < off) red[threadIdx.x] += red[threadIdx.x + off];
        __syncthreads();
    }
    if (threadIdx.x == 0) g[bc] = red[0] * (1.0f / (HH * WW));
}

// ---------------- K2: gating MLP + softmax + top2 + coef + loss --------
__global__ __launch_bounds__(512) void gate_kernel(const float* __restrict__ g,
                                                   const float* __restrict__ gw1,
                                                   const float* __restrict__ gb1,
                                                   const float* __restrict__ gw2,
                                                   const float* __restrict__ gb2,
                                                   float* __restrict__ coef_out,
                                                   float* __restrict__ loss_out) {
    __shared__ float h[BATCH][HID];
    __shared__ float logits[BATCH][NE];
    int t = threadIdx.x;  // 512 threads
    // hidden layer: h[b][t] = relu(sum_c g[b][c]*gw1[t][c] + gb1[t])
    for (int b = 0; b < BATCH; b++) {
        float acc = gb1[t];
        for (int c = 0; c < CH; c++) acc = fmaf(g[b * CH + c], gw1[t * CH + c], acc);
        h[b][t] = fmaxf(acc, 0.f);
    }
    __syncthreads();
    // output layer: logits[b][e]
    if (t < BATCH * NE) {
        int b = t / NE, e = t % NE;
        float acc = gb2[e];
        for (int j = 0; j < HID; j++) acc = fmaf(h[b][j], gw2[e * HID + j], acc);
        logits[b][e] = acc;
    }
    __syncthreads();
    if (t == 0) {
        float sm[BATCH][NE];
        for (int b = 0; b < BATCH; b++) {
            float m = logits[b][0];
            for (int e = 1; e < NE; e++) m = fmaxf(m, logits[b][e]);
            float s = 0.f;
            for (int e = 0; e < NE; e++) { sm[b][e] = expf(logits[b][e] - m); s += sm[b][e]; }
            for (int e = 0; e < NE; e++) sm[b][e] /= s;
        }
        // loss = std(sm, ddof=1) / (mean(sm)+eps) * 0.1
        float mean = 0.f;
        for (int b = 0; b < BATCH; b++)
            for (int e = 0; e < NE; e++) mean += sm[b][e];
        mean *= 1.0f / (BATCH * NE);
        float var = 0.f;
        for (int b = 0; b < BATCH; b++)
            for (int e = 0; e < NE; e++) {
                float d = sm[b][e] - mean;
                var += d * d;
            }
        var *= 1.0f / (BATCH * NE - 1);
        *loss_out = sqrtf(var) / (mean + 1e-10f) * 0.1f;
        // top-2 per batch row, softmax over the two vals, accumulate coef
        float coef[NE] = {0.f, 0.f, 0.f, 0.f};
        for (int b = 0; b < BATCH; b++) {
            int i0 = 0;
            for (int e = 1; e < NE; e++)
                if (sm[b][e] > sm[b][i0]) i0 = e;
            int i1 = -1;
            for (int e = 0; e < NE; e++) {
                if (e == i0) continue;
                if (i1 < 0 || sm[b][e] > sm[b][i1]) i1 = e;
            }
            float v0 = sm[b][i0], v1 = sm[b][i1];  // v0 >= v1, descending like top_k
            float be = expf(v1 - v0);
            float a0 = 1.f / (1.f + be);
            float a1 = be / (1.f + be);
            coef[i0] += a0;
            coef[i1] += a1;
        }
        for (int e = 0; e < NE; e++) coef_out[e] = coef[e];
    }
}

// ---------------- K3: fused 4-expert direct conv + sigmoid + mix -------
// One block per (b, c_out, y) row: c_out/ci/dy uniform per block -> weight
// loads become scalar (s_load); x loads are coalesced along the row.
__global__ __launch_bounds__(256) void conv_kernel(const float* __restrict__ x,
                                                   const float* __restrict__ ew1,
                                                   const float* __restrict__ eb1,
                                                   const float* __restrict__ ew3,
                                                   const float* __restrict__ eb3,
                                                   const float* __restrict__ ew7,
                                                   const float* __restrict__ eb7,
                                                   const float* __restrict__ ew11,
                                                   const float* __restrict__ eb11,
                                                   const float* __restrict__ coef,
                                                   float* __restrict__ out) {
    int blk = blockIdx.x;       // b*CH*HH + c*HH + y
    int y = blk & (HH - 1);
    int c = (blk >> 8) & (CH - 1);
    int b = blk >> 14;
    int xi = threadIdx.x;       // column 0..255
    const size_t plane = (size_t)HH * WW;

    float a0 = 0.f, a1 = 0.f, a2 = 0.f, a3 = 0.f;

    for (int dy = 0; dy < 11; dy++) {
        int yy = y + dy - 5;
        if (yy < 0 || yy >= HH) continue;  // zero padding row
        bool in7y = (dy >= 2 && dy <= 8);
        bool in3y = (dy >= 4 && dy <= 6);
        bool in1y = (dy == 5);
        for (int ci = 0; ci < CH; ci++) {
            const float* xrow = x + ((size_t)(b * CH + ci)) * plane + (size_t)yy * WW;
            const float* w11row = ew11 + (((c * CH + ci) * 11 + dy) * 11);
            const float* w7row = in7y ? (ew7 + (((c * CH + ci) * 7 + (dy - 2)) * 7)) : ew7;
            const float* w3row = in3y ? (ew3 + (((c * CH + ci) * 3 + (dy - 4)) * 3)) : ew3;
            float w1v = in1y ? ew1[c * CH + ci] : 0.f;
#pragma unroll
            for (int dx = 0; dx < 11; dx++) {
                int xc = xi + dx - 5;
                float xv = (xc >= 0 && xc < WW) ? xrow[xc] : 0.f;
                a3 = fmaf(w11row[dx], xv, a3);
                if (dx >= 2 && dx <= 8) {
                    if (in7y) a2 = fmaf(w7row[dx - 2], xv, a2);
                }
                if (dx >= 4 && dx <= 6) {
                    if (in3y) a1 = fmaf(w3row[dx - 4], xv, a1);
                }
                if (dx == 5) {
                    if (in1y) a0 = fmaf(w1v, xv, a0);
                }
            }
        }
    }

    a0 += eb1[c];
    a1 += eb3[c];
    a2 += eb7[c];
    a3 += eb11[c];
    float s0 = 1.f / (1.f + expf(-a0));
    float s1 = 1.f / (1.f + expf(-a1));
    float s2 = 1.f / (1.f + expf(-a2));
    float s3 = 1.f / (1.f + expf(-a3));
    float mix = coef[0] * s0 + coef[1] * s1 + coef[2] * s2 + coef[3] * s3;

    size_t idx = ((size_t)(b * CH + c)) * plane + (size_t)y * WW + xi;
    out[idx] = x[idx] * mix;
}

extern "C" void kernel_launch(void* const* d_in, const int* in_sizes, int n_in,
                              void* d_out, int out_size, void* d_ws, size_t ws_size,
                              hipStream_t stream) {
    const float* x = (const float*)d_in[0];
    const float* gw1 = (const float*)d_in[1];
    const float* gb1 = (const float*)d_in[2];
    const float* gw2 = (const float*)d_in[3];
    const float* gb2 = (const float*)d_in[4];
    const float* ew1 = (const float*)d_in[5];
    const float* eb1 = (const float*)d_in[6];
    const float* ew3 = (const float*)d_in[7];
    const float* eb3 = (const float*)d_in[8];
    const float* ew7 = (const float*)d_in[9];
    const float* eb7 = (const float*)d_in[10];
    const float* ew11 = (const float*)d_in[11];
    const float* eb11 = (const float*)d_in[12];

    float* out = (float*)d_out;
    float* wsf = (float*)d_ws;
    float* g = wsf;            // 512 floats
    float* coef = wsf + 512;   // 4 floats
    float* loss_out = out + (out_size - 1);  // loss scalar after the tensor

    mean_kernel<<<BATCH * CH, 256, 0, stream>>>(x, g);
    gate_kernel<<<1, 512, 0, stream>>>(g, gw1, gb1, gw2, gb2, coef, loss_out);
    conv_kernel<<<BATCH * CH * HH, 256, 0, stream>>>(x, ew1, eb1, ew3, eb3, ew7, eb7,
                                                     ew11, eb11, coef, out);
}

// Round 2
// 4412.871 us; speedup vs baseline: 16.8585x; 16.8585x over previous
//
#include <hip/hip_runtime.h>
#include <hip/hip_bf16.h>
#include <math.h>

#define BATCH 8
#define CH 64
#define HH 256
#define WW 256
#define HID 512
#define NE 4

typedef short v8s __attribute__((ext_vector_type(8)));
typedef float v4f __attribute__((ext_vector_type(4)));

static __device__ __forceinline__ unsigned short f2bf(float v) {
    __hip_bfloat16 h = __float2bfloat16(v);
    return *(unsigned short*)&h;
}

// ---------------- K1: per-(b,c) spatial mean -> g[8*64] ----------------
__global__ __launch_bounds__(256) void mean_kernel(const float* __restrict__ x,
                                                   float* __restrict__ g) {
    int bc = blockIdx.x;
    const float* p = x + (size_t)bc * (HH * WW);
    float s = 0.f;
    for (int i = threadIdx.x; i < HH * WW; i += 256) s += p[i];
    __shared__ float red[256];
    red[threadIdx.x] = s;
    __syncthreads();
    for (int off = 128; off > 0; off >>= 1) {
        if (threadIdx.x < off) red[threadIdx.x] += red[threadIdx.x + off];
        __syncthreads();
    }
    if (threadIdx.x == 0) g[bc] = red[0] * (1.0f / (HH * WW));
}

// ---------------- K2: gating MLP + softmax + top2 + coef + loss --------
__global__ __launch_bounds__(512) void gate_kernel(const float* __restrict__ g,
                                                   const float* __restrict__ gw1,
                                                   const float* __restrict__ gb1,
                                                   const float* __restrict__ gw2,
                                                   const float* __restrict__ gb2,
                                                   float* __restrict__ coef_out,
                                                   float* __restrict__ loss_out) {
    __shared__ float h[BATCH][HID];
    __shared__ float logits[BATCH][NE];
    int t = threadIdx.x;
    for (int b = 0; b < BATCH; b++) {
        float acc = gb1[t];
        for (int c = 0; c < CH; c++) acc = fmaf(g[b * CH + c], gw1[t * CH + c], acc);
        h[b][t] = fmaxf(acc, 0.f);
    }
    __syncthreads();
    if (t < BATCH * NE) {
        int b = t / NE, e = t % NE;
        float acc = gb2[e];
        for (int j = 0; j < HID; j++) acc = fmaf(h[b][j], gw2[e * HID + j], acc);
        logits[b][e] = acc;
    }
    __syncthreads();
    if (t == 0) {
        float sm[BATCH][NE];
        for (int b = 0; b < BATCH; b++) {
            float m = logits[b][0];
            for (int e = 1; e < NE; e++) m = fmaxf(m, logits[b][e]);
            float s = 0.f;
            for (int e = 0; e < NE; e++) { sm[b][e] = expf(logits[b][e] - m); s += sm[b][e]; }
            for (int e = 0; e < NE; e++) sm[b][e] /= s;
        }
        float mean = 0.f;
        for (int b = 0; b < BATCH; b++)
            for (int e = 0; e < NE; e++) mean += sm[b][e];
        mean *= 1.0f / (BATCH * NE);
        float var = 0.f;
        for (int b = 0; b < BATCH; b++)
            for (int e = 0; e < NE; e++) {
                float d = sm[b][e] - mean;
                var += d * d;
            }
        var *= 1.0f / (BATCH * NE - 1);
        *loss_out = sqrtf(var) / (mean + 1e-10f) * 0.1f;
        float coef[NE] = {0.f, 0.f, 0.f, 0.f};
        for (int b = 0; b < BATCH; b++) {
            int i0 = 0;
            for (int e = 1; e < NE; e++)
                if (sm[b][e] > sm[b][i0]) i0 = e;
            int i1 = -1;
            for (int e = 0; e < NE; e++) {
                if (e == i0) continue;
                if (i1 < 0 || sm[b][e] > sm[b][i1]) i1 = e;
            }
            float v0 = sm[b][i0], v1 = sm[b][i1];
            float be = expf(v1 - v0);
            float a0 = 1.f / (1.f + be);
            float a1 = be / (1.f + be);
            coef[i0] += a0;
            coef[i1] += a1;
        }
        for (int e = 0; e < NE; e++) coef_out[e] = coef[e];
    }
}

// ---------------- K3a: weights OIHW fp32 -> wT[e][tap][co][ci] bf16 ----
// expert tap blocks (4096 elems each): e1 @0 (1 tap), e3 @1 (9), e7 @10 (49), e11 @59 (121)
__global__ __launch_bounds__(256) void wtrans_kernel(const float* __restrict__ ew1,
                                                     const float* __restrict__ ew3,
                                                     const float* __restrict__ ew7,
                                                     const float* __restrict__ ew11,
                                                     unsigned short* __restrict__ wT) {
    int gid = blockIdx.x * 256 + threadIdx.x;  // < 180*512 = 92160
    int tapg = gid >> 9;
    int rem = gid & 511;
    int co = rem >> 3, kg = rem & 7;
    const float* src;
    int k, tap, dstbase;
    if (tapg < 1) { src = ew1; k = 1; tap = tapg; dstbase = 0; }
    else if (tapg < 10) { src = ew3; k = 3; tap = tapg - 1; dstbase = 1 * 4096; }
    else if (tapg < 59) { src = ew7; k = 7; tap = tapg - 10; dstbase = 10 * 4096; }
    else { src = ew11; k = 11; tap = tapg - 59; dstbase = 59 * 4096; }
    int ky = tap / k, kx = tap - ky * k;
    unsigned short o[8];
#pragma unroll
    for (int j = 0; j < 8; j++) {
        int ci = kg * 8 + j;
        o[j] = f2bf(src[((co * 64 + ci) * k + ky) * k + kx]);
    }
    *(v8s*)(wT + (size_t)dstbase + ((size_t)tap * 64 + co) * 64 + kg * 8) = *(v8s*)o;
}

// ---------------- K3b: x NCHW fp32 -> xT[b][y][x][ci] bf16 -------------
#define XP 258
__global__ __launch_bounds__(256) void xtrans_kernel(const float* __restrict__ x,
                                                     unsigned short* __restrict__ xT) {
    __shared__ unsigned short t[64 * XP];
    int blk = blockIdx.x;  // b*256 + y
    int b = blk >> 8, y = blk & 255;
    int tid = threadIdx.x;
    for (int ci = 0; ci < 64; ci++) {
        float v = x[((size_t)(b * 64 + ci)) * 65536 + (size_t)y * 256 + tid];
        t[ci * XP + tid] = f2bf(v);
    }
    __syncthreads();
    unsigned short* dst = xT + (size_t)blk * 256 * 64;
    for (int c = tid; c < 2048; c += 256) {
        int xx = c >> 3, kg = c & 7;
        unsigned short o[8];
#pragma unroll
        for (int j = 0; j < 8; j++) o[j] = t[(kg * 8 + j) * XP + xx];
        *(v8s*)(dst + (size_t)xx * 64 + kg * 8) = *(v8s*)o;
    }
}

// ---------------- K4: MFMA implicit-GEMM fused 4-expert conv -----------
// block = (b, ytile, xtile): 8x8 pixels x 64 co. 4 waves; wave w owns co
// [w*16, w*16+16). LDS: 18x18 px halo x 64 ci bf16, pixel stride 72 elems.
__global__ __launch_bounds__(256) void moe_mfma_kernel(
        const unsigned short* __restrict__ xT, const unsigned short* __restrict__ wT,
        const float* __restrict__ x,
        const float* __restrict__ eb1, const float* __restrict__ eb3,
        const float* __restrict__ eb7, const float* __restrict__ eb11,
        const float* __restrict__ coef, float* __restrict__ out) {
    __shared__ unsigned short sx[324 * 72];  // 46656 B
    int blk = blockIdx.x;
    int xt = blk & 31, yt = (blk >> 5) & 31, b = blk >> 10;
    int x0 = xt * 8, y0 = yt * 8;
    int tid = threadIdx.x;

    // ---- stage halo tile (guarded zero padding) ----
    for (int i = tid; i < 2592; i += 256) {
        int row = i / 144;
        int rem = i - row * 144;
        int px = rem >> 3, kg = rem & 7;
        int gy = y0 - 5 + row, gx = x0 - 5 + px;
        v8s v = {0, 0, 0, 0, 0, 0, 0, 0};
        if ((unsigned)gy < 256u && (unsigned)gx < 256u)
            v = *(const v8s*)(xT + (((size_t)(b * 256 + gy) * 256 + gx) * 64 + kg * 8));
        *(v8s*)(sx + (size_t)(row * 18 + px) * 72 + kg * 8) = v;
    }
    __syncthreads();

    int wave = tid >> 6, lane = tid & 63;
    int ml = lane & 15, kgrp = lane >> 4;
    int cobase = wave * 16;
    int co = cobase + ml;

    // per-mt lane LDS element offsets
    int lane_off[4];
#pragma unroll
    for (int mt = 0; mt < 4; mt++) {
        int py = mt * 2 + (ml >> 3);
        int px = ml & 7;
        lane_off[mt] = (py * 18 + px) * 72 + kgrp * 8;
    }
    int laneB = co * 64 + kgrp * 8;
    const unsigned short* wT1 = wT;
    const unsigned short* wT3 = wT + 4096;
    const unsigned short* wT7 = wT + 10 * 4096;
    const unsigned short* wT11 = wT + 59 * 4096;

    v4f acc[4][4];  // [expert][mtile]
#pragma unroll
    for (int e = 0; e < 4; e++)
#pragma unroll
        for (int mt = 0; mt < 4; mt++) acc[e][mt] = (v4f){0.f, 0.f, 0.f, 0.f};

    for (int dy = 0; dy < 11; dy++) {
        bool y7 = (dy >= 2 && dy <= 8), y3 = (dy >= 4 && dy <= 6), y1 = (dy == 5);
        for (int dx = 0; dx < 11; dx++) {
            int tapoff = (dy * 18 + dx) * 72;
            bool in7 = y7 && (dx >= 2 && dx <= 8);
            bool in3 = y3 && (dx >= 4 && dx <= 6);
            bool in1 = y1 && (dx == 5);
            const unsigned short* wb11 = wT11 + (size_t)(dy * 11 + dx) * 4096 + laneB;
            const unsigned short* wb7 = wT7 + (size_t)((dy - 2) * 7 + (dx - 2)) * 4096 + laneB;
            const unsigned short* wb3 = wT3 + (size_t)((dy - 4) * 3 + (dx - 4)) * 4096 + laneB;
            const unsigned short* wb1 = wT1 + laneB;
#pragma unroll
            for (int kc = 0; kc < 2; kc++) {
                v8s a0 = *(const v8s*)(sx + lane_off[0] + tapoff + kc * 32);
                v8s a1 = *(const v8s*)(sx + lane_off[1] + tapoff + kc * 32);
                v8s a2 = *(const v8s*)(sx + lane_off[2] + tapoff + kc * 32);
                v8s a3 = *(const v8s*)(sx + lane_off[3] + tapoff + kc * 32);
                v8s bb = *(const v8s*)(wb11 + kc * 32);
                acc[3][0] = __builtin_amdgcn_mfma_f32_16x16x32_bf16(a0, bb, acc[3][0], 0, 0, 0);
                acc[3][1] = __builtin_amdgcn_mfma_f32_16x16x32_bf16(a1, bb, acc[3][1], 0, 0, 0);
                acc[3][2] = __builtin_amdgcn_mfma_f32_16x16x32_bf16(a2, bb, acc[3][2], 0, 0, 0);
                acc[3][3] = __builtin_amdgcn_mfma_f32_16x16x32_bf16(a3, bb, acc[3][3], 0, 0, 0);
                if (in7) {
                    v8s b7 = *(const v8s*)(wb7 + kc * 32);
                    acc[2][0] = __builtin_amdgcn_mfma_f32_16x16x32_bf16(a0, b7, acc[2][0], 0, 0, 0);
                    acc[2][1] = __builtin_amdgcn_mfma_f32_16x16x32_bf16(a1, b7, acc[2][1], 0, 0, 0);
                    acc[2][2] = __builtin_amdgcn_mfma_f32_16x16x32_bf16(a2, b7, acc[2][2], 0, 0, 0);
                    acc[2][3] = __builtin_amdgcn_mfma_f32_16x16x32_bf16(a3, b7, acc[2][3], 0, 0, 0);
                }
                if (in3) {
                    v8s b3 = *(const v8s*)(wb3 + kc * 32);
                    acc[1][0] = __builtin_amdgcn_mfma_f32_16x16x32_bf16(a0, b3, acc[1][0], 0, 0, 0);
                    acc[1][1] = __builtin_amdgcn_mfma_f32_16x16x32_bf16(a1, b3, acc[1][1], 0, 0, 0);
                    acc[1][2] = __builtin_amdgcn_mfma_f32_16x16x32_bf16(a2, b3, acc[1][2], 0, 0, 0);
                    acc[1][3] = __builtin_amdgcn_mfma_f32_16x16x32_bf16(a3, b3, acc[1][3], 0, 0, 0);
                }
                if (in1) {
                    v8s b1 = *(const v8s*)(wb1 + kc * 32);
                    acc[0][0] = __builtin_amdgcn_mfma_f32_16x16x32_bf16(a0, b1, acc[0][0], 0, 0, 0);
                    acc[0][1] = __builtin_amdgcn_mfma_f32_16x16x32_bf16(a1, b1, acc[0][1], 0, 0, 0);
                    acc[0][2] = __builtin_amdgcn_mfma_f32_16x16x32_bf16(a2, b1, acc[0][2], 0, 0, 0);
                    acc[0][3] = __builtin_amdgcn_mfma_f32_16x16x32_bf16(a3, b1, acc[0][3], 0, 0, 0);
                }
            }
        }
    }

    // ---- epilogue: bias + sigmoid + coef mix + multiply by x ----
    float c0 = coef[0], c1 = coef[1], c2 = coef[2], c3 = coef[3];
    float b0 = eb1[co], b1 = eb3[co], b2 = eb7[co], b3 = eb11[co];
    size_t planebase = ((size_t)(b * 64 + co)) * 65536;
#pragma unroll
    for (int mt = 0; mt < 4; mt++) {
        int mbase = mt * 16 + kgrp * 4;
        int py = mbase >> 3, pxb = mbase & 7;
        size_t off = planebase + (size_t)(y0 + py) * 256 + (size_t)(x0 + pxb);
        v4f xv = *(const v4f*)(x + off);
        v4f o;
#pragma unroll
        for (int r = 0; r < 4; r++) {
            float s0 = 1.f / (1.f + expf(-(acc[0][mt][r] + b0)));
            float s1 = 1.f / (1.f + expf(-(acc[1][mt][r] + b1)));
            float s2 = 1.f / (1.f + expf(-(acc[2][mt][r] + b2)));
            float s3 = 1.f / (1.f + expf(-(acc[3][mt][r] + b3)));
            float mix = c0 * s0 + c1 * s1 + c2 * s2 + c3 * s3;
            o[r] = xv[r] * mix;
        }
        *(v4f*)(out + off) = o;
    }
}

// ---------------- fallback direct conv (R1, verified) ------------------
__global__ __launch_bounds__(256) void conv_kernel(const float* __restrict__ x,
                                                   const float* __restrict__ ew1,
                                                   const float* __restrict__ eb1,
                                                   const float* __restrict__ ew3,
                                                   const float* __restrict__ eb3,
                                                   const float* __restrict__ ew7,
                                                   const float* __restrict__ eb7,
                                                   const float* __restrict__ ew11,
                                                   const float* __restrict__ eb11,
                                                   const float* __restrict__ coef,
                                                   float* __restrict__ out) {
    int blk = blockIdx.x;
    int y = blk & (HH - 1);
    int c = (blk >> 8) & (CH - 1);
    int b = blk >> 14;
    int xi = threadIdx.x;
    const size_t plane = (size_t)HH * WW;
    float a0 = 0.f, a1 = 0.f, a2 = 0.f, a3 = 0.f;
    for (int dy = 0; dy < 11; dy++) {
        int yy = y + dy - 5;
        if (yy < 0 || yy >= HH) continue;
        bool in7y = (dy >= 2 && dy <= 8);
        bool in3y = (dy >= 4 && dy <= 6);
        bool in1y = (dy == 5);
        for (int ci = 0; ci < CH; ci++) {
            const float* xrow = x + ((size_t)(b * CH + ci)) * plane + (size_t)yy * WW;
            const float* w11row = ew11 + (((c * CH + ci) * 11 + dy) * 11);
            const float* w7row = in7y ? (ew7 + (((c * CH + ci) * 7 + (dy - 2)) * 7)) : ew7;
            const float* w3row = in3y ? (ew3 + (((c * CH + ci) * 3 + (dy - 4)) * 3)) : ew3;
            float w1v = in1y ? ew1[c * CH + ci] : 0.f;
#pragma unroll
            for (int dx = 0; dx < 11; dx++) {
                int xc = xi + dx - 5;
                float xv = (xc >= 0 && xc < WW) ? xrow[xc] : 0.f;
                a3 = fmaf(w11row[dx], xv, a3);
                if (dx >= 2 && dx <= 8) { if (in7y) a2 = fmaf(w7row[dx - 2], xv, a2); }
                if (dx >= 4 && dx <= 6) { if (in3y) a1 = fmaf(w3row[dx - 4], xv, a1); }
                if (dx == 5) { if (in1y) a0 = fmaf(w1v, xv, a0); }
            }
        }
    }
    a0 += eb1[c]; a1 += eb3[c]; a2 += eb7[c]; a3 += eb11[c];
    float s0 = 1.f / (1.f + expf(-a0));
    float s1 = 1.f / (1.f + expf(-a1));
    float s2 = 1.f / (1.f + expf(-a2));
    float s3 = 1.f / (1.f + expf(-a3));
    float mix = coef[0] * s0 + coef[1] * s1 + coef[2] * s2 + coef[3] * s3;
    size_t idx = ((size_t)(b * CH + c)) * plane + (size_t)y * WW + xi;
    out[idx] = x[idx] * mix;
}

extern "C" void kernel_launch(void* const* d_in, const int* in_sizes, int n_in,
                              void* d_out, int out_size, void* d_ws, size_t ws_size,
                              hipStream_t stream) {
    const float* x = (const float*)d_in[0];
    const float* gw1 = (const float*)d_in[1];
    const float* gb1 = (const float*)d_in[2];
    const float* gw2 = (const float*)d_in[3];
    const float* gb2 = (const float*)d_in[4];
    const float* ew1 = (const float*)d_in[5];
    const float* eb1 = (const float*)d_in[6];
    const float* ew3 = (const float*)d_in[7];
    const float* eb3 = (const float*)d_in[8];
    const float* ew7 = (const float*)d_in[9];
    const float* eb7 = (const float*)d_in[10];
    const float* ew11 = (const float*)d_in[11];
    const float* eb11 = (const float*)d_in[12];

    float* out = (float*)d_out;
    float* wsf = (float*)d_ws;
    float* g = wsf;                                // 512 floats
    float* coef = wsf + 512;                       // 4 floats (+pad to 520)
    unsigned short* wT = (unsigned short*)((char*)d_ws + 2080);       // 737280 bf16
    unsigned short* xT = (unsigned short*)((char*)d_ws + 1476640);    // 33.55M bf16
    float* loss_out = out + (out_size - 1);
    const size_t need = 1476640ull + 67108864ull;

    mean_kernel<<<BATCH * CH, 256, 0, stream>>>(x, g);
    gate_kernel<<<1, 512, 0, stream>>>(g, gw1, gb1, gw2, gb2, coef, loss_out);

    if (ws_size >= need) {
        wtrans_kernel<<<360, 256, 0, stream>>>(ew1, ew3, ew7, ew11, wT);
        xtrans_kernel<<<BATCH * HH, 256, 0, stream>>>(x, xT);
        moe_mfma_kernel<<<8192, 256, 0, stream>>>(xT, wT, x, eb1, eb3, eb7, eb11, coef, out);
    } else {
        conv_kernel<<<BATCH * CH * HH, 256, 0, stream>>>(x, ew1, eb1, ew3, eb3, ew7, eb7,
                                                         ew11, eb11, coef, out);
    }
}

// Round 3
// 2982.590 us; speedup vs baseline: 24.9429x; 1.4795x over previous
//
#include <hip/hip_runtime.h>
#include <hip/hip_bf16.h>
#include <math.h>

#define BATCH 8
#define CH 64
#define HH 256
#define WW 256
#define HID 512
#define NE 4

typedef short v8s __attribute__((ext_vector_type(8)));
typedef float v4f __attribute__((ext_vector_type(4)));
typedef float v16f __attribute__((ext_vector_type(16)));

static __device__ __forceinline__ unsigned short f2bf(float v) {
    __hip_bfloat16 h = __float2bfloat16(v);
    return *(unsigned short*)&h;
}

// ---------------- K1: per-(b,c) spatial mean -> g[8*64] ----------------
__global__ __launch_bounds__(256) void mean_kernel(const float* __restrict__ x,
                                                   float* __restrict__ g) {
    int bc = blockIdx.x;
    const float* p = x + (size_t)bc * (HH * WW);
    float s = 0.f;
    for (int i = threadIdx.x; i < HH * WW; i += 256) s += p[i];
    __shared__ float red[256];
    red[threadIdx.x] = s;
    __syncthreads();
    for (int off = 128; off > 0; off >>= 1) {
        if (threadIdx.x < off) red[threadIdx.x] += red[threadIdx.x + off];
        __syncthreads();
    }
    if (threadIdx.x == 0) g[bc] = red[0] * (1.0f / (HH * WW));
}

// ---------------- K2: gating MLP + softmax + top2 + coef + loss --------
__global__ __launch_bounds__(512) void gate_kernel(const float* __restrict__ g,
                                                   const float* __restrict__ gw1,
                                                   const float* __restrict__ gb1,
                                                   const float* __restrict__ gw2,
                                                   const float* __restrict__ gb2,
                                                   float* __restrict__ coef_out,
                                                   float* __restrict__ loss_out) {
    __shared__ float h[BATCH][HID];
    __shared__ float logits[BATCH][NE];
    int t = threadIdx.x;
    for (int b = 0; b < BATCH; b++) {
        float acc = gb1[t];
        for (int c = 0; c < CH; c++) acc = fmaf(g[b * CH + c], gw1[t * CH + c], acc);
        h[b][t] = fmaxf(acc, 0.f);
    }
    __syncthreads();
    if (t < BATCH * NE) {
        int b = t / NE, e = t % NE;
        float acc = gb2[e];
        for (int j = 0; j < HID; j++) acc = fmaf(h[b][j], gw2[e * HID + j], acc);
        logits[b][e] = acc;
    }
    __syncthreads();
    if (t == 0) {
        float sm[BATCH][NE];
        for (int b = 0; b < BATCH; b++) {
            float m = logits[b][0];
            for (int e = 1; e < NE; e++) m = fmaxf(m, logits[b][e]);
            float s = 0.f;
            for (int e = 0; e < NE; e++) { sm[b][e] = expf(logits[b][e] - m); s += sm[b][e]; }
            for (int e = 0; e < NE; e++) sm[b][e] /= s;
        }
        float mean = 0.f;
        for (int b = 0; b < BATCH; b++)
            for (int e = 0; e < NE; e++) mean += sm[b][e];
        mean *= 1.0f / (BATCH * NE);
        float var = 0.f;
        for (int b = 0; b < BATCH; b++)
            for (int e = 0; e < NE; e++) {
                float d = sm[b][e] - mean;
                var += d * d;
            }
        var *= 1.0f / (BATCH * NE - 1);
        *loss_out = sqrtf(var) / (mean + 1e-10f) * 0.1f;
        float coef[NE] = {0.f, 0.f, 0.f, 0.f};
        for (int b = 0; b < BATCH; b++) {
            int i0 = 0;
            for (int e = 1; e < NE; e++)
                if (sm[b][e] > sm[b][i0]) i0 = e;
            int i1 = -1;
            for (int e = 0; e < NE; e++) {
                if (e == i0) continue;
                if (i1 < 0 || sm[b][e] > sm[b][i1]) i1 = e;
            }
            float v0 = sm[b][i0], v1 = sm[b][i1];
            float be = expf(v1 - v0);
            float a0 = 1.f / (1.f + be);
            float a1 = be / (1.f + be);
            coef[i0] += a0;
            coef[i1] += a1;
        }
        for (int e = 0; e < NE; e++) coef_out[e] = coef[e];
    }
}

// ---------------- K3a: weights OIHW fp32 -> wT[e][tap][co][ci] bf16 ----
__global__ __launch_bounds__(256) void wtrans_kernel(const float* __restrict__ ew1,
                                                     const float* __restrict__ ew3,
                                                     const float* __restrict__ ew7,
                                                     const float* __restrict__ ew11,
                                                     unsigned short* __restrict__ wT) {
    int gid = blockIdx.x * 256 + threadIdx.x;  // < 180*512 = 92160
    int tapg = gid >> 9;
    int rem = gid & 511;
    int co = rem >> 3, kg = rem & 7;
    const float* src;
    int k, tap, dstbase;
    if (tapg < 1) { src = ew1; k = 1; tap = tapg; dstbase = 0; }
    else if (tapg < 10) { src = ew3; k = 3; tap = tapg - 1; dstbase = 1 * 4096; }
    else if (tapg < 59) { src = ew7; k = 7; tap = tapg - 10; dstbase = 10 * 4096; }
    else { src = ew11; k = 11; tap = tapg - 59; dstbase = 59 * 4096; }
    int ky = tap / k, kx = tap - ky * k;
    unsigned short o[8];
#pragma unroll
    for (int j = 0; j < 8; j++) {
        int ci = kg * 8 + j;
        o[j] = f2bf(src[((co * 64 + ci) * k + ky) * k + kx]);
    }
    *(v8s*)(wT + (size_t)dstbase + ((size_t)tap * 64 + co) * 64 + kg * 8) = *(v8s*)o;
}

// ---------------- K3b: x NCHW fp32 -> xT[b][y][x][ci] bf16 -------------
#define XP 258
__global__ __launch_bounds__(256) void xtrans_kernel(const float* __restrict__ x,
                                                     unsigned short* __restrict__ xT) {
    __shared__ unsigned short t[64 * XP];
    int blk = blockIdx.x;  // b*256 + y
    int b = blk >> 8, y = blk & 255;
    int tid = threadIdx.x;
    for (int ci = 0; ci < 64; ci++) {
        float v = x[((size_t)(b * 64 + ci)) * 65536 + (size_t)y * 256 + tid];
        t[ci * XP + tid] = f2bf(v);
    }
    __syncthreads();
    unsigned short* dst = xT + (size_t)blk * 256 * 64;
    for (int c = tid; c < 2048; c += 256) {
        int xx = c >> 3, kg = c & 7;
        unsigned short o[8];
#pragma unroll
        for (int j = 0; j < 8; j++) o[j] = t[(kg * 8 + j) * XP + xx];
        *(v8s*)(dst + (size_t)xx * 64 + kg * 8) = *(v8s*)o;
    }
}

// ---------------- K4: 32x32x16 MFMA expert-sequential fused conv -------
// block = (b, ytile16, xtile8): 16x8 px, 64 co. 4 waves; wave w = rows
// [w*4, w*4+4) x 8 cols = 32 px (MFMA m), all 64 co = 2 n-tiles.
// LDS halo: 26 rows x 18 cols x 64 ci bf16 = 59904 B, 128 B/px, chunk-XOR
// swizzle: 16B chunk c (=kc*2+kh) of pixel p stored at bit0=kh,
// upper2 = kc ^ (p&3). (p&3) under p+=18*dy folds to q ^ ((dy&1)<<1).
__device__ __forceinline__ v16f mfma32(v8s a, v8s b, v16f c) {
    return __builtin_amdgcn_mfma_f32_32x32x16_bf16(a, b, c, 0, 0, 0);
}

template <int KS, int OFF, int CIDX>
__device__ __forceinline__ void expert_pass(const unsigned short* sx,
                                            const unsigned short* wTe,
                                            const float* __restrict__ eb,
                                            const float* __restrict__ coef,
                                            int p00, int kh, int n,
                                            int boffB0, int boffB1,
                                            v16f& mix0, v16f& mix1) {
    v16f a0 = {};
    v16f a1 = {};
    int pD = p00 + OFF * 19;           // halo px at (dy=0,dx=0) of this expert
    int baseB = pD * 128 + kh * 16;    // byte offset in LDS (no swizzle term)
    for (int dx = 0; dx < KS; ++dx) {
        int q = (pD + dx) & 3;
        int t0 = q << 5;
        int aq[4];
        aq[0] = baseB + t0;
        aq[1] = baseB + (t0 ^ 32);
        aq[2] = baseB + (t0 ^ 64);
        aq[3] = baseB + (t0 ^ 96);
#pragma unroll
        for (int dy = 0; dy < KS; ++dy) {
            const int sw = (dy & 1) << 1;
            const int ro = dy * 2304;  // 18 px * 128 B
            v8s A0 = *(const v8s*)((const char*)sx + aq[0 ^ sw] + ro);
            v8s A1 = *(const v8s*)((const char*)sx + aq[1 ^ sw] + ro);
            v8s A2 = *(const v8s*)((const char*)sx + aq[2 ^ sw] + ro);
            v8s A3 = *(const v8s*)((const char*)sx + aq[3 ^ sw] + ro);
            const char* wp = (const char*)wTe + (size_t)(dy * KS + dx) * 8192;
            v8s B00 = *(const v8s*)(wp + boffB0);
            v8s B01 = *(const v8s*)(wp + boffB0 + 32);
            v8s B02 = *(const v8s*)(wp + boffB0 + 64);
            v8s B03 = *(const v8s*)(wp + boffB0 + 96);
            v8s B10 = *(const v8s*)(wp + boffB1);
            v8s B11 = *(const v8s*)(wp + boffB1 + 32);
            v8s B12 = *(const v8s*)(wp + boffB1 + 64);
            v8s B13 = *(const v8s*)(wp + boffB1 + 96);
            a0 = mfma32(A0, B00, a0);
            a0 = mfma32(A1, B01, a0);
            a0 = mfma32(A2, B02, a0);
            a0 = mfma32(A3, B03, a0);
            a1 = mfma32(A0, B10, a1);
            a1 = mfma32(A1, B11, a1);
            a1 = mfma32(A2, B12, a1);
            a1 = mfma32(A3, B13, a1);
        }
        baseB += 128;
    }
    // fold this expert into the mix: mix += coef * sigmoid(acc + bias)
    float ce = coef[CIDX];
    float b0v = eb[n];
    float b1v = eb[32 + n];
#pragma unroll
    for (int r = 0; r < 16; ++r) {
        float z0 = a0[r] + b0v;
        float z1 = a1[r] + b1v;
        mix0[r] = fmaf(ce, 1.f / (1.f + __expf(-z0)), mix0[r]);
        mix1[r] = fmaf(ce, 1.f / (1.f + __expf(-z1)), mix1[r]);
    }
}

__global__ __launch_bounds__(256) void moe32_kernel(
        const unsigned short* __restrict__ xT, const unsigned short* __restrict__ wT,
        const float* __restrict__ x,
        const float* __restrict__ eb1, const float* __restrict__ eb3,
        const float* __restrict__ eb7, const float* __restrict__ eb11,
        const float* __restrict__ coef, float* __restrict__ out) {
    __shared__ unsigned short sx[26 * 18 * 64];  // 59904 B
    int blk = blockIdx.x;
    int xt = blk & 31, yt = (blk >> 5) & 15, b = blk >> 9;
    int x0 = xt * 8, y0 = yt * 16;
    int tid = threadIdx.x;

    // ---- stage swizzled halo ----
    for (int i = tid; i < 3744; i += 256) {
        int hrow = i / 144;
        int rem = i - hrow * 144;
        int hcol = rem >> 3, c = rem & 7;
        int px = hrow * 18 + hcol;
        int gy = y0 + hrow - 5, gx = x0 + hcol - 5;
        v8s v = {0, 0, 0, 0, 0, 0, 0, 0};
        if ((unsigned)gy < 256u && (unsigned)gx < 256u)
            v = *(const v8s*)(xT + (((size_t)(b * 256 + gy) * 256 + gx) * 64 + c * 8));
        int cs = (c & 1) | ((((c >> 1) ^ px) & 3) << 1);
        *(v8s*)(sx + px * 64 + cs * 8) = v;
    }
    __syncthreads();

    int lane = tid & 63, w = tid >> 6;
    int kh = lane >> 5, n = lane & 31;
    int prow = (lane & 31) >> 3, pcol = lane & 7;
    int p00 = (w * 4 + prow) * 18 + pcol;  // halo px of this lane's pixel at tap origin
    int boffB0 = n * 128 + kh * 16;        // bytes into a tap's [co][ci] block
    int boffB1 = (32 + n) * 128 + kh * 16;

    v16f mix0 = {};
    v16f mix1 = {};

    const unsigned short* wT1 = wT;
    const unsigned short* wT3 = wT + 4096;
    const unsigned short* wT7 = wT + 10 * 4096;
    const unsigned short* wT11 = wT + 59 * 4096;

    expert_pass<11, 0, 3>(sx, wT11, eb11, coef, p00, kh, n, boffB0, boffB1, mix0, mix1);
    expert_pass<7, 2, 2>(sx, wT7, eb7, coef, p00, kh, n, boffB0, boffB1, mix0, mix1);
    expert_pass<3, 4, 1>(sx, wT3, eb3, coef, p00, kh, n, boffB0, boffB1, mix0, mix1);
    expert_pass<1, 5, 0>(sx, wT1, eb1, coef, p00, kh, n, boffB0, boffB1, mix0, mix1);

    // ---- final: out = x * mix ----
    size_t pb0 = ((size_t)(b * 64 + n)) * 65536;
    size_t pb1 = ((size_t)(b * 64 + 32 + n)) * 65536;
    int yb = y0 + w * 4, xb = x0 + kh * 4;
#pragma unroll
    for (int g = 0; g < 4; ++g) {
        size_t off = (size_t)(yb + g) * 256 + xb;
        v4f xv0 = *(const v4f*)(x + pb0 + off);
        v4f xv1 = *(const v4f*)(x + pb1 + off);
        v4f o0, o1;
#pragma unroll
        for (int r = 0; r < 4; ++r) {
            o0[r] = xv0[r] * mix0[g * 4 + r];
            o1[r] = xv1[r] * mix1[g * 4 + r];
        }
        *(v4f*)(out + pb0 + off) = o0;
        *(v4f*)(out + pb1 + off) = o1;
    }
}

// ---------------- fallback direct conv (R1, verified) ------------------
__global__ __launch_bounds__(256) void conv_kernel(const float* __restrict__ x,
                                                   const float* __restrict__ ew1,
                                                   const float* __restrict__ eb1,
                                                   const float* __restrict__ ew3,
                                                   const float* __restrict__ eb3,
                                                   const float* __restrict__ ew7,
                                                   const float* __restrict__ eb7,
                                                   const float* __restrict__ ew11,
                                                   const float* __restrict__ eb11,
                                                   const float* __restrict__ coef,
                                                   float* __restrict__ out) {
    int blk = blockIdx.x;
    int y = blk & (HH - 1);
    int c = (blk >> 8) & (CH - 1);
    int b = blk >> 14;
    int xi = threadIdx.x;
    const size_t plane = (size_t)HH * WW;
    float a0 = 0.f, a1 = 0.f, a2 = 0.f, a3 = 0.f;
    for (int dy = 0; dy < 11; dy++) {
        int yy = y + dy - 5;
        if (yy < 0 || yy >= HH) continue;
        bool in7y = (dy >= 2 && dy <= 8);
        bool in3y = (dy >= 4 && dy <= 6);
        bool in1y = (dy == 5);
        for (int ci = 0; ci < CH; ci++) {
            const float* xrow = x + ((size_t)(b * CH + ci)) * plane + (size_t)yy * WW;
            const float* w11row = ew11 + (((c * CH + ci) * 11 + dy) * 11);
            const float* w7row = in7y ? (ew7 + (((c * CH + ci) * 7 + (dy - 2)) * 7)) : ew7;
            const float* w3row = in3y ? (ew3 + (((c * CH + ci) * 3 + (dy - 4)) * 3)) : ew3;
            float w1v = in1y ? ew1[c * CH + ci] : 0.f;
#pragma unroll
            for (int dx = 0; dx < 11; dx++) {
                int xc = xi + dx - 5;
                float xv = (xc >= 0 && xc < WW) ? xrow[xc] : 0.f;
                a3 = fmaf(w11row[dx], xv, a3);
                if (dx >= 2 && dx <= 8) { if (in7y) a2 = fmaf(w7row[dx - 2], xv, a2); }
                if (dx >= 4 && dx <= 6) { if (in3y) a1 = fmaf(w3row[dx - 4], xv, a1); }
                if (dx == 5) { if (in1y) a0 = fmaf(w1v, xv, a0); }
            }
        }
    }
    a0 += eb1[c]; a1 += eb3[c]; a2 += eb7[c]; a3 += eb11[c];
    float s0 = 1.f / (1.f + expf(-a0));
    float s1 = 1.f / (1.f + expf(-a1));
    float s2 = 1.f / (1.f + expf(-a2));
    float s3 = 1.f / (1.f + expf(-a3));
    float mix = coef[0] * s0 + coef[1] * s1 + coef[2] * s2 + coef[3] * s3;
    size_t idx = ((size_t)(b * CH + c)) * plane + (size_t)y * WW + xi;
    out[idx] = x[idx] * mix;
}

extern "C" void kernel_launch(void* const* d_in, const int* in_sizes, int n_in,
                              void* d_out, int out_size, void* d_ws, size_t ws_size,
                              hipStream_t stream) {
    const float* x = (const float*)d_in[0];
    const float* gw1 = (const float*)d_in[1];
    const float* gb1 = (const float*)d_in[2];
    const float* gw2 = (const float*)d_in[3];
    const float* gb2 = (const float*)d_in[4];
    const float* ew1 = (const float*)d_in[5];
    const float* eb1 = (const float*)d_in[6];
    const float* ew3 = (const float*)d_in[7];
    const float* eb3 = (const float*)d_in[8];
    const float* ew7 = (const float*)d_in[9];
    const float* eb7 = (const float*)d_in[10];
    const float* ew11 = (const float*)d_in[11];
    const float* eb11 = (const float*)d_in[12];

    float* out = (float*)d_out;
    float* wsf = (float*)d_ws;
    float* g = wsf;                                // 512 floats
    float* coef = wsf + 512;                       // 4 floats (+pad to 520)
    unsigned short* wT = (unsigned short*)((char*)d_ws + 2080);       // 737280 bf16
    unsigned short* xT = (unsigned short*)((char*)d_ws + 1476640);    // 33.55M bf16
    float* loss_out = out + (out_size - 1);
    const size_t need = 1476640ull + 67108864ull;

    mean_kernel<<<BATCH * CH, 256, 0, stream>>>(x, g);
    gate_kernel<<<1, 512, 0, stream>>>(g, gw1, gb1, gw2, gb2, coef, loss_out);

    if (ws_size >= need) {
        wtrans_kernel<<<360, 256, 0, stream>>>(ew1, ew3, ew7, ew11, wT);
        xtrans_kernel<<<BATCH * HH, 256, 0, stream>>>(x, xT);
        moe32_kernel<<<4096, 256, 0, stream>>>(xT, wT, x, eb1, eb3, eb7, eb11, coef, out);
    } else {
        conv_kernel<<<BATCH * CH * HH, 256, 0, stream>>>(x, ew1, eb1, ew3, eb3, ew7, eb7,
                                                         ew11, eb11, coef, out);
    }
}